// Round 11
// baseline (362.458 us; speedup 1.0000x reference)
//
#include <hip/hip_runtime.h>

// GCN 2-layer forward — R9 7-dispatch structure (in-graph boundary ~1us;
// R8/R10 proved on-device cross-workgroup sync costs 10-100x that).
// R11: pull1 made band-major to kill per-XCD L2 refetch of h:
//   - k_bsort now insertion-sorts each row's edge segment by src
//   - k_pull1: persistent, 7 rows/wave, register accumulators + cursors,
//     sweeps 8 src-bands (band = N/8 rows of h ~ 1.6MB bf16) so all
//     resident blocks touch the same 1-2 bands at a time (fits 4MB XCD L2).
// Pipeline: L1 combo(gemm1 MFMA || hist partials) -> L2 scanB -> L3 partition
//           -> L4 bsort(+src-sort) -> L5 pull1(banded) -> L6 gemm2 -> L7 pull2

typedef unsigned int uint32;
typedef unsigned short u16;
typedef __attribute__((ext_vector_type(8))) short bf16x8;
typedef __attribute__((ext_vector_type(4))) float f32x4;

#define NBMAX 1024
#define CHUNK 4096
#define EH 8192   // edges per hist block
#define RPW 7     // rows per wave in pull1

__device__ inline u16 bf16rn(float f) {
    unsigned u = __float_as_uint(f);
    return (u16)((u + 0x7fffu + ((u >> 16) & 1u)) >> 16);
}

__device__ inline void bffma(float2& a, float w, uint32 u) {
    a.x = fmaf(w, __uint_as_float(u << 16), a.x);
    a.y = fmaf(w, __uint_as_float(u & 0xffff0000u), a.y);
}

// ---- L1: gemm1 tiles || hist partial histograms ---------------------------
__global__ __launch_bounds__(256) void k_combo(
    const float* __restrict__ x, const float* __restrict__ W1,
    const int* __restrict__ dstv, int* __restrict__ partials,
    u16* __restrict__ h, int N, int E, int NB, int ntile)
{
    __shared__ __align__(16) unsigned char smem[128 * 136 * 2];  // 34816 B
    int t = threadIdx.x;

    if ((int)blockIdx.x >= ntile) {
        int* hl = (int*)smem;
        int hb = blockIdx.x - ntile;
        int e0 = hb * EH, e1 = min(e0 + EH, E);
        for (int i = t; i < NB; i += 256) hl[i] = 0;
        __syncthreads();
        for (int e = e0 + t; e < e1; e += 256)
            atomicAdd(&hl[dstv[e] >> 8], 1);
        __syncthreads();
        int* pr = partials + (size_t)hb * NBMAX;
        for (int i = t; i < NB; i += 256) pr[i] = hl[i];
        return;
    }

    // gemm1: h[N,128](bf16) = x @ W1, MFMA 16x16x32, W1 staged once
    u16* Wl = (u16*)smem;  // [n][k] pitch 136 (2-way bank aliasing: free)
    const float4* Wg4 = (const float4*)W1;
    for (int g = t; g < 128 * 32; g += 256) {
        int k = g >> 5, n4 = (g & 31) * 4;
        float4 v = Wg4[g];
        Wl[(n4 + 0) * 136 + k] = bf16rn(v.x);
        Wl[(n4 + 1) * 136 + k] = bf16rn(v.y);
        Wl[(n4 + 2) * 136 + k] = bf16rn(v.z);
        Wl[(n4 + 3) * 136 + k] = bf16rn(v.w);
    }
    __syncthreads();

    int wave = t >> 6, lane = t & 63;
    int quad = lane >> 4, ln = lane & 15;
    int rowbase = blockIdx.x * 64 + wave * 16;
    int rclamp = min(rowbase + ln, N - 1);

    f32x4 acc[8];
    #pragma unroll
    for (int ct = 0; ct < 8; ++ct) acc[ct] = (f32x4){0.f, 0.f, 0.f, 0.f};

    #pragma unroll
    for (int q = 0; q < 4; ++q) {
        const float4* xr = (const float4*)(x + (size_t)rclamp * 128 + q * 32 + quad * 8);
        float4 a0 = xr[0], a1 = xr[1];
        bf16x8 afr;
        afr[0] = (short)bf16rn(a0.x); afr[1] = (short)bf16rn(a0.y);
        afr[2] = (short)bf16rn(a0.z); afr[3] = (short)bf16rn(a0.w);
        afr[4] = (short)bf16rn(a1.x); afr[5] = (short)bf16rn(a1.y);
        afr[6] = (short)bf16rn(a1.z); afr[7] = (short)bf16rn(a1.w);
        #pragma unroll
        for (int ct = 0; ct < 8; ++ct) {
            bf16x8 bfr = *(const bf16x8*)&Wl[(ct * 16 + ln) * 136 + q * 32 + quad * 8];
            acc[ct] = __builtin_amdgcn_mfma_f32_16x16x32_bf16(afr, bfr, acc[ct], 0, 0, 0);
        }
    }
    #pragma unroll
    for (int i = 0; i < 4; ++i) {
        int r = rowbase + quad * 4 + i;
        if (r < N) {
            u16* hp = h + (size_t)r * 128 + ln;
            #pragma unroll
            for (int ct = 0; ct < 8; ++ct)
                hp[ct * 16] = bf16rn(acc[ct][i]);
        }
    }
}

// ---- L2: reduce partials, exclusive scan, zero bfill ----------------------
__global__ __launch_bounds__(1024) void k_scanB(
    const int* __restrict__ partials, int* __restrict__ bbase,
    int* __restrict__ bfill, int NB, int E, int NH)
{
    __shared__ int s[1024];
    int t = threadIdx.x;
    int v = 0;
    if (t < NB)
        for (int p = 0; p < NH; ++p) v += partials[(size_t)p * NBMAX + t];
    s[t] = v;
    __syncthreads();
    for (int off = 1; off < 1024; off <<= 1) {
        int u = (t >= off) ? s[t - off] : 0;
        __syncthreads();
        s[t] += u;
        __syncthreads();
    }
    if (t < NB) {
        bbase[t] = s[t] - v;
        bfill[t] = 0;
    }
    if (t == 0) bbase[NB] = E;
}

// ---- L3: partition edges into bucket regions ------------------------------
__global__ __launch_bounds__(256) void k_partition(
    const int* __restrict__ src, const int* __restrict__ dstv,
    const int* __restrict__ bbase, int* __restrict__ bfill,
    int2* __restrict__ tmp, int E, int NB)
{
    __shared__ int cntL[NBMAX];
    __shared__ int baseL[NBMAX];
    int t = threadIdx.x;
    int e0 = blockIdx.x * CHUNK;
    int e1 = min(e0 + CHUNK, E);
    for (int i = t; i < NB; i += 256) cntL[i] = 0;
    __syncthreads();
    for (int e = e0 + t; e < e1; e += 256)
        atomicAdd(&cntL[dstv[e] >> 8], 1);
    __syncthreads();
    for (int i = t; i < NB; i += 256) {
        int cc = cntL[i];
        baseL[i] = cc ? bbase[i] + atomicAdd(&bfill[i], cc) : 0;
        cntL[i] = 0;
    }
    __syncthreads();
    for (int e = e0 + t; e < e1; e += 256) {
        int sv = src[e], d = dstv[e];
        int b = d >> 8;
        int r = atomicAdd(&cntL[b], 1);
        tmp[baseL[b] + r] = make_int2(sv, d);
    }
}

// ---- L4: per-bucket sort by dst; then sort each row's srcs ascending ------
__global__ __launch_bounds__(256) void k_bsort(
    const int2* __restrict__ tmp, const int* __restrict__ bbase,
    int* __restrict__ ssrc, int* __restrict__ rs,
    float* __restrict__ dinv, int N)
{
    __shared__ int cnt[256];
    __shared__ int ofs[256];
    int t = threadIdx.x;
    int b = blockIdx.x;
    int base = bbase[b];
    int endb = bbase[b + 1];
    int node0 = b << 8;

    cnt[t] = 0;
    __syncthreads();
    for (int i = base + t; i < endb; i += 256)
        atomicAdd(&cnt[tmp[i].y & 255], 1);
    __syncthreads();
    int v = cnt[t];
    __syncthreads();
    for (int off = 1; off < 256; off <<= 1) {
        int u = (t >= off) ? cnt[t - off] : 0;
        __syncthreads();
        cnt[t] += u;
        __syncthreads();
    }
    int node = node0 + t;
    if (node < N) {
        dinv[node] = rsqrtf(fmaxf((float)v, 1.0f));
        rs[node] = base + cnt[t];
    }
    int start = base + cnt[t] - v;
    ofs[t] = start;
    __syncthreads();
    for (int i = base + t; i < endb; i += 256) {
        int2 rec = tmp[i];
        int pos = atomicAdd(&ofs[rec.y & 255], 1);
        ssrc[pos] = rec.x;
    }
    __syncthreads();
    // insertion-sort this row's segment by src (enables banded pull1; sums
    // are order-invariant so output unchanged up to fp32 rounding)
    for (int i = start + 1; i < start + v; ++i) {
        int key = ssrc[i];
        int j = i - 1;
        while (j >= start && ssrc[j] > key) {
            ssrc[j + 1] = ssrc[j];
            --j;
        }
        ssrc[j + 1] = key;
    }
}

// ---- L5: pull1 banded — out1[n,:] (bf16x2) = sum_e w_e * h[src_e,:] -------
// 7 rows/wave, register acc + cursors; sweep 8 src-bands so concurrent
// blocks share an L2-resident slice of h (~1.6MB/band).
__global__ __launch_bounds__(256) void k_pull1(
    const int* __restrict__ rs, const int* __restrict__ ssrc,
    const float* __restrict__ dinv, const uint32* __restrict__ h,
    uint32* __restrict__ out1, int N, int BS)
{
    int wave = threadIdx.x >> 6, lane = threadIdx.x & 63;
    int gw = blockIdx.x * 4 + wave;
    int r0 = gw * RPW;
    if (r0 >= N) return;

    float2 acc[RPW];
    int jj[RPW], ee[RPW];
    float dn[RPW];
    #pragma unroll
    for (int i = 0; i < RPW; ++i) {
        acc[i] = (float2){0.f, 0.f};
        int n = r0 + i;
        if (n < N) {
            jj[i] = __builtin_amdgcn_readfirstlane((n == 0) ? 0 : rs[n - 1]);
            ee[i] = __builtin_amdgcn_readfirstlane(rs[n]);
            dn[i] = dinv[n];
        } else {
            jj[i] = 0; ee[i] = 0; dn[i] = 0.f;
        }
    }

    #pragma unroll
    for (int b = 0; b < 8; ++b) {
        int bandEnd = (b == 7) ? 0x7fffffff : (b + 1) * BS;
        #pragma unroll
        for (int i = 0; i < RPW; ++i) {
            int j = jj[i], e = ee[i];
            float d = dn[i];
            while (j < e) {
                int s = __builtin_amdgcn_readfirstlane(ssrc[j]);
                if (s >= bandEnd) break;
                float w = d * dinv[s];
                bffma(acc[i], w, h[(size_t)s * 64 + lane]);
                ++j;
            }
            jj[i] = j;
        }
    }

    #pragma unroll
    for (int i = 0; i < RPW; ++i) {
        int n = r0 + i;
        if (n < N)
            out1[(size_t)n * 64 + lane] =
                ((uint32)bf16rn(acc[i].y) << 16) | bf16rn(acc[i].x);
    }
}

// ---- L6: gemm2 — h2[N,16](bf16) = relu(out1+b1) @ W2 ----------------------
__global__ __launch_bounds__(256) void k_gemm2(
    const uint32* __restrict__ out1, const float* __restrict__ b1,
    const float* __restrict__ W2, u16* __restrict__ h2, int N)
{
    __shared__ float W2T[16 * 132];
    __shared__ float b1l[128];
    __shared__ float al[32 * 132];
    int t = threadIdx.x;
    int row0 = blockIdx.x * 32;

    for (int g = t; g < 2048; g += 256) {
        int k = g >> 4, f = g & 15;
        W2T[f * 132 + k] = W2[g];
    }
    if (t < 128) b1l[t] = b1[t];
    __syncthreads();

    float4* al4 = (float4*)al;
    const uint4* o4 = (const uint4*)out1;
    for (int g = t; g < 32 * 16; g += 256) {
        int r = g >> 4, k8 = g & 15;
        uint4 u = {0u, 0u, 0u, 0u};
        if (row0 + r < N) u = o4[(size_t)(row0 + r) * 16 + k8];
        const float* bb = &b1l[k8 * 8];
        float4 v0, v1;
        v0.x = fmaxf(__uint_as_float(u.x << 16)         + bb[0], 0.f);
        v0.y = fmaxf(__uint_as_float(u.x & 0xffff0000u) + bb[1], 0.f);
        v0.z = fmaxf(__uint_as_float(u.y << 16)         + bb[2], 0.f);
        v0.w = fmaxf(__uint_as_float(u.y & 0xffff0000u) + bb[3], 0.f);
        v1.x = fmaxf(__uint_as_float(u.z << 16)         + bb[4], 0.f);
        v1.y = fmaxf(__uint_as_float(u.z & 0xffff0000u) + bb[5], 0.f);
        v1.z = fmaxf(__uint_as_float(u.w << 16)         + bb[6], 0.f);
        v1.w = fmaxf(__uint_as_float(u.w & 0xffff0000u) + bb[7], 0.f);
        al4[r * 33 + k8 * 2]     = v0;
        al4[r * 33 + k8 * 2 + 1] = v1;
    }
    __syncthreads();

    int f = t & 15, r0 = t >> 4;
    const float4* W4 = (const float4*)W2T;
    float acc0 = 0.f, acc1 = 0.f;
    #pragma unroll 8
    for (int k4 = 0; k4 < 32; ++k4) {
        float4 w  = W4[f * 33 + k4];
        float4 x0 = al4[r0 * 33 + k4];
        float4 x1 = al4[(r0 + 16) * 33 + k4];
        acc0 = fmaf(x0.x, w.x, acc0); acc0 = fmaf(x0.y, w.y, acc0);
        acc0 = fmaf(x0.z, w.z, acc0); acc0 = fmaf(x0.w, w.w, acc0);
        acc1 = fmaf(x1.x, w.x, acc1); acc1 = fmaf(x1.y, w.y, acc1);
        acc1 = fmaf(x1.z, w.z, acc1); acc1 = fmaf(x1.w, w.w, acc1);
    }
    if (row0 + r0 < N)      h2[(size_t)(row0 + r0) * 16 + f] = bf16rn(acc0);
    if (row0 + r0 + 16 < N) h2[(size_t)(row0 + r0 + 16) * 16 + f] = bf16rn(acc1);
}

// ---- L7: pull2 + log_softmax (8 lanes/row, 2 classes/lane) ----------------
__global__ __launch_bounds__(256) void k_pull2(
    const int* __restrict__ rs, const int* __restrict__ ssrc,
    const float* __restrict__ dinv, const uint32* __restrict__ h2,
    const float* __restrict__ b2, float* __restrict__ out, int N)
{
    int idx = blockIdx.x * 256 + threadIdx.x;
    int n = idx >> 3;
    if (n >= N) return;
    int c = idx & 7;
    int start = (n == 0) ? 0 : rs[n - 1];
    int end = rs[n];
    float dn = dinv[n];
    float acc0 = 0.f, acc1 = 0.f;
    for (int j = start; j < end; ++j) {
        int s = ssrc[j];
        float w = dn * dinv[s];
        uint32 u = h2[(size_t)s * 8 + c];
        acc0 = fmaf(w, __uint_as_float(u << 16), acc0);
        acc1 = fmaf(w, __uint_as_float(u & 0xffff0000u), acc1);
    }
    float v0 = acc0 + b2[2 * c];
    float v1 = acc1 + b2[2 * c + 1];
    float m = fmaxf(v0, v1);
    #pragma unroll
    for (int off = 1; off < 8; off <<= 1) m = fmaxf(m, __shfl_xor(m, off));
    float s = expf(v0 - m) + expf(v1 - m);
    #pragma unroll
    for (int off = 1; off < 8; off <<= 1) s += __shfl_xor(s, off);
    float ls = logf(s);
    float2 r = {v0 - m - ls, v1 - m - ls};
    ((float2*)out)[(size_t)n * 8 + c] = r;
}

extern "C" void kernel_launch(void* const* d_in, const int* in_sizes, int n_in,
                              void* d_out, int out_size, void* d_ws, size_t ws_size,
                              hipStream_t stream) {
    const float* x  = (const float*)d_in[0];
    const int*   ei = (const int*)d_in[1];
    const float* W1 = (const float*)d_in[2];
    const float* b1 = (const float*)d_in[3];
    const float* W2 = (const float*)d_in[4];
    const float* b2 = (const float*)d_in[5];
    float* outp = (float*)d_out;

    const int E = in_sizes[1] / 2;
    const int N = in_sizes[0] / 128;
    const int NB = (N + 255) >> 8;
    const int NH = (E + EH - 1) / EH;
    const int ntile = (N + 63) / 64;
    const int BS = (N + 7) / 8;   // src band size
    const int* src  = ei;
    const int* dstv = ei + E;

    const int Npad = (N + 255) & ~255;
    const int Epad = (E + 255) & ~255;
    int*   partials = (int*)d_ws;                   // [NH(<=128)][NBMAX]
    int*   bbase = partials + 128 * NBMAX;          // [NBMAX+1] (+pad)
    int*   bfill = bbase + NBMAX + 256;             // [NBMAX]
    int*   rs    = bfill + NBMAX;                   // [Npad]
    float* dinv  = (float*)(rs + Npad);             // [Npad]
    int2*  tmp   = (int2*)(dinv + Npad);            // [Epad]
    int*   ssrc  = (int*)(tmp + Epad);              // [Epad]
    u16*   h     = (u16*)(ssrc + Epad);             // N*128 bf16 (aliased h2)
    uint32* out1 = (uint32*)(h + (size_t)N * 128);  // N*64 packed bf16x2
    u16*   h2    = h;

    k_combo<<<ntile + NH, 256, 0, stream>>>(x, W1, dstv, partials, h, N, E, NB, ntile);
    k_scanB<<<1, 1024, 0, stream>>>(partials, bbase, bfill, NB, E, NH);
    k_partition<<<(E + CHUNK - 1) / CHUNK, 256, 0, stream>>>(src, dstv, bbase,
                                                             bfill, tmp, E, NB);
    k_bsort<<<NB, 256, 0, stream>>>(tmp, bbase, ssrc, rs, dinv, N);
    k_pull1<<<(N + 4 * RPW - 1) / (4 * RPW), 256, 0, stream>>>(
        rs, ssrc, dinv, (const uint32*)h, out1, N, BS);
    k_gemm2<<<(N + 31) / 32, 256, 0, stream>>>(out1, b1, W2, h2, N);
    k_pull2<<<(N * 8 + 255) / 256, 256, 0, stream>>>(rs, ssrc, dinv,
                                                     (const uint32*)h2, b2, outp, N);
}

// Round 12
// 200.865 us; speedup vs baseline: 1.8045x; 1.8045x over previous
//
#include <hip/hip_runtime.h>

// GCN 2-layer forward — R9 7-dispatch structure (in-graph boundary ~1us;
// R8/R10: on-device cross-workgroup sync is 10-100x worse; R11: serial
// global-memory insertion sort = latency poison, reverted).
// R12: pull1 -> 2 rows per wave (half-wave per row, uint2 payload loads):
//   one VMEM inst moves 512B across 2 rows; wave count halves; 12 loads
//   in flight per unroll group. Everything else identical to R9.
// Pipeline: L1 combo(gemm1 MFMA || hist partials) -> L2 scanB -> L3 partition
//           -> L4 bsort -> L5 pull1 -> L6 gemm2 -> L7 pull2+log_softmax

typedef unsigned int uint32;
typedef unsigned short u16;
typedef __attribute__((ext_vector_type(8))) short bf16x8;
typedef __attribute__((ext_vector_type(4))) float f32x4;

#define NBMAX 1024
#define CHUNK 4096
#define EH 8192   // edges per hist block

__device__ inline u16 bf16rn(float f) {
    unsigned u = __float_as_uint(f);
    return (u16)((u + 0x7fffu + ((u >> 16) & 1u)) >> 16);
}

__device__ inline void bffma(float2& a, float w, uint32 u) {
    a.x = fmaf(w, __uint_as_float(u << 16), a.x);
    a.y = fmaf(w, __uint_as_float(u & 0xffff0000u), a.y);
}

// ---- L1: gemm1 tiles || hist partial histograms ---------------------------
__global__ __launch_bounds__(256) void k_combo(
    const float* __restrict__ x, const float* __restrict__ W1,
    const int* __restrict__ dstv, int* __restrict__ partials,
    u16* __restrict__ h, int N, int E, int NB, int ntile)
{
    __shared__ __align__(16) unsigned char smem[128 * 136 * 2];  // 34816 B
    int t = threadIdx.x;

    if ((int)blockIdx.x >= ntile) {
        int* hl = (int*)smem;
        int hb = blockIdx.x - ntile;
        int e0 = hb * EH, e1 = min(e0 + EH, E);
        for (int i = t; i < NB; i += 256) hl[i] = 0;
        __syncthreads();
        for (int e = e0 + t; e < e1; e += 256)
            atomicAdd(&hl[dstv[e] >> 8], 1);
        __syncthreads();
        int* pr = partials + (size_t)hb * NBMAX;
        for (int i = t; i < NB; i += 256) pr[i] = hl[i];
        return;
    }

    // gemm1: h[N,128](bf16) = x @ W1, MFMA 16x16x32, W1 staged once
    u16* Wl = (u16*)smem;  // [n][k] pitch 136 (2-way bank aliasing: free)
    const float4* Wg4 = (const float4*)W1;
    for (int g = t; g < 128 * 32; g += 256) {
        int k = g >> 5, n4 = (g & 31) * 4;
        float4 v = Wg4[g];
        Wl[(n4 + 0) * 136 + k] = bf16rn(v.x);
        Wl[(n4 + 1) * 136 + k] = bf16rn(v.y);
        Wl[(n4 + 2) * 136 + k] = bf16rn(v.z);
        Wl[(n4 + 3) * 136 + k] = bf16rn(v.w);
    }
    __syncthreads();

    int wave = t >> 6, lane = t & 63;
    int quad = lane >> 4, ln = lane & 15;
    int rowbase = blockIdx.x * 64 + wave * 16;
    int rclamp = min(rowbase + ln, N - 1);

    f32x4 acc[8];
    #pragma unroll
    for (int ct = 0; ct < 8; ++ct) acc[ct] = (f32x4){0.f, 0.f, 0.f, 0.f};

    #pragma unroll
    for (int q = 0; q < 4; ++q) {
        const float4* xr = (const float4*)(x + (size_t)rclamp * 128 + q * 32 + quad * 8);
        float4 a0 = xr[0], a1 = xr[1];
        bf16x8 afr;
        afr[0] = (short)bf16rn(a0.x); afr[1] = (short)bf16rn(a0.y);
        afr[2] = (short)bf16rn(a0.z); afr[3] = (short)bf16rn(a0.w);
        afr[4] = (short)bf16rn(a1.x); afr[5] = (short)bf16rn(a1.y);
        afr[6] = (short)bf16rn(a1.z); afr[7] = (short)bf16rn(a1.w);
        #pragma unroll
        for (int ct = 0; ct < 8; ++ct) {
            bf16x8 bfr = *(const bf16x8*)&Wl[(ct * 16 + ln) * 136 + q * 32 + quad * 8];
            acc[ct] = __builtin_amdgcn_mfma_f32_16x16x32_bf16(afr, bfr, acc[ct], 0, 0, 0);
        }
    }
    #pragma unroll
    for (int i = 0; i < 4; ++i) {
        int r = rowbase + quad * 4 + i;
        if (r < N) {
            u16* hp = h + (size_t)r * 128 + ln;
            #pragma unroll
            for (int ct = 0; ct < 8; ++ct)
                hp[ct * 16] = bf16rn(acc[ct][i]);
        }
    }
}

// ---- L2: reduce partials, exclusive scan, zero bfill ----------------------
__global__ __launch_bounds__(1024) void k_scanB(
    const int* __restrict__ partials, int* __restrict__ bbase,
    int* __restrict__ bfill, int NB, int E, int NH)
{
    __shared__ int s[1024];
    int t = threadIdx.x;
    int v = 0;
    if (t < NB)
        for (int p = 0; p < NH; ++p) v += partials[(size_t)p * NBMAX + t];
    s[t] = v;
    __syncthreads();
    for (int off = 1; off < 1024; off <<= 1) {
        int u = (t >= off) ? s[t - off] : 0;
        __syncthreads();
        s[t] += u;
        __syncthreads();
    }
    if (t < NB) {
        bbase[t] = s[t] - v;
        bfill[t] = 0;
    }
    if (t == 0) bbase[NB] = E;
}

// ---- L3: partition edges into bucket regions ------------------------------
__global__ __launch_bounds__(256) void k_partition(
    const int* __restrict__ src, const int* __restrict__ dstv,
    const int* __restrict__ bbase, int* __restrict__ bfill,
    int2* __restrict__ tmp, int E, int NB)
{
    __shared__ int cntL[NBMAX];
    __shared__ int baseL[NBMAX];
    int t = threadIdx.x;
    int e0 = blockIdx.x * CHUNK;
    int e1 = min(e0 + CHUNK, E);
    for (int i = t; i < NB; i += 256) cntL[i] = 0;
    __syncthreads();
    for (int e = e0 + t; e < e1; e += 256)
        atomicAdd(&cntL[dstv[e] >> 8], 1);
    __syncthreads();
    for (int i = t; i < NB; i += 256) {
        int cc = cntL[i];
        baseL[i] = cc ? bbase[i] + atomicAdd(&bfill[i], cc) : 0;
        cntL[i] = 0;
    }
    __syncthreads();
    for (int e = e0 + t; e < e1; e += 256) {
        int sv = src[e], d = dstv[e];
        int b = d >> 8;
        int r = atomicAdd(&cntL[b], 1);
        tmp[baseL[b] + r] = make_int2(sv, d);
    }
}

// ---- L4: per-bucket exact sort; emit dinv / rs / ssrc ---------------------
__global__ __launch_bounds__(256) void k_bsort(
    const int2* __restrict__ tmp, const int* __restrict__ bbase,
    int* __restrict__ ssrc, int* __restrict__ rs,
    float* __restrict__ dinv, int N)
{
    __shared__ int cnt[256];
    __shared__ int ofs[256];
    int t = threadIdx.x;
    int b = blockIdx.x;
    int base = bbase[b];
    int endb = bbase[b + 1];
    int node0 = b << 8;

    cnt[t] = 0;
    __syncthreads();
    for (int i = base + t; i < endb; i += 256)
        atomicAdd(&cnt[tmp[i].y & 255], 1);
    __syncthreads();
    int v = cnt[t];
    __syncthreads();
    for (int off = 1; off < 256; off <<= 1) {
        int u = (t >= off) ? cnt[t - off] : 0;
        __syncthreads();
        cnt[t] += u;
        __syncthreads();
    }
    int node = node0 + t;
    if (node < N) {
        dinv[node] = rsqrtf(fmaxf((float)v, 1.0f));
        rs[node] = base + cnt[t];
    }
    ofs[t] = base + cnt[t] - v;
    __syncthreads();
    for (int i = base + t; i < endb; i += 256) {
        int2 rec = tmp[i];
        int pos = atomicAdd(&ofs[rec.y & 255], 1);
        ssrc[pos] = rec.x;
    }
}

// ---- L5: pull1 — 2 rows/wave (half-wave per row), uint2 payload loads -----
// out1[n,:] (bf16x2) = sum_{e in row n} dinv[n]*dinv[src]*h[src,:]
__global__ __launch_bounds__(256) void k_pull1(
    const int* __restrict__ rs, const int* __restrict__ ssrc,
    const float* __restrict__ dinv, const uint2* __restrict__ h,
    uint2* __restrict__ out1, int N)
{
    int wid = (blockIdx.x * 256 + threadIdx.x) >> 6;
    if (wid * 2 >= N) return;
    int lane = threadIdx.x & 63;
    int sub = lane >> 5;      // which row of the pair
    int rl = lane & 31;       // lane within half-wave (covers 32 uint2 = row)
    int n = wid * 2 + sub;
    bool valid = (n < N);
    int nc = valid ? n : 0;
    int start = valid ? ((nc == 0) ? 0 : rs[nc - 1]) : 0;
    int len   = valid ? (rs[nc] - start) : 0;
    float dn  = valid ? dinv[nc] : 0.f;
    int lenMax = max(len, __shfl_xor(len, 32));

    float2 aA[4], aB[4];
    #pragma unroll
    for (int k = 0; k < 4; ++k) {
        aA[k] = (float2){0.f, 0.f};
        aB[k] = (float2){0.f, 0.f};
    }

    for (int tt = 0; tt < lenMax; tt += 4) {
        int s[4];
        uint2 u[4];
        float w[4];
        #pragma unroll
        for (int k = 0; k < 4; ++k) {
            bool act = (tt + k) < len;            // uniform per half-wave
            int jj = act ? (start + tt + k) : 0;  // index 0 always valid
            s[k] = ssrc[jj];
            w[k] = act ? 1.f : 0.f;
        }
        #pragma unroll
        for (int k = 0; k < 4; ++k)
            u[k] = h[(size_t)s[k] * 32 + rl];
        #pragma unroll
        for (int k = 0; k < 4; ++k)
            w[k] *= dn * dinv[s[k]];
        #pragma unroll
        for (int k = 0; k < 4; ++k) {
            bffma(aA[k], w[k], u[k].x);
            bffma(aB[k], w[k], u[k].y);
        }
    }

    if (valid) {
        float2 A, B;
        A.x = (aA[0].x + aA[1].x) + (aA[2].x + aA[3].x);
        A.y = (aA[0].y + aA[1].y) + (aA[2].y + aA[3].y);
        B.x = (aB[0].x + aB[1].x) + (aB[2].x + aB[3].x);
        B.y = (aB[0].y + aB[1].y) + (aB[2].y + aB[3].y);
        uint2 o;
        o.x = ((uint32)bf16rn(A.y) << 16) | bf16rn(A.x);
        o.y = ((uint32)bf16rn(B.y) << 16) | bf16rn(B.x);
        out1[(size_t)n * 32 + rl] = o;
    }
}

// ---- L6: gemm2 — h2[N,16](bf16) = relu(out1+b1) @ W2 ----------------------
__global__ __launch_bounds__(256) void k_gemm2(
    const uint32* __restrict__ out1, const float* __restrict__ b1,
    const float* __restrict__ W2, u16* __restrict__ h2, int N)
{
    __shared__ float W2T[16 * 132];
    __shared__ float b1l[128];
    __shared__ float al[32 * 132];
    int t = threadIdx.x;
    int row0 = blockIdx.x * 32;

    for (int g = t; g < 2048; g += 256) {
        int k = g >> 4, f = g & 15;
        W2T[f * 132 + k] = W2[g];
    }
    if (t < 128) b1l[t] = b1[t];
    __syncthreads();

    float4* al4 = (float4*)al;
    const uint4* o4 = (const uint4*)out1;
    for (int g = t; g < 32 * 16; g += 256) {
        int r = g >> 4, k8 = g & 15;
        uint4 u = {0u, 0u, 0u, 0u};
        if (row0 + r < N) u = o4[(size_t)(row0 + r) * 16 + k8];
        const float* bb = &b1l[k8 * 8];
        float4 v0, v1;
        v0.x = fmaxf(__uint_as_float(u.x << 16)         + bb[0], 0.f);
        v0.y = fmaxf(__uint_as_float(u.x & 0xffff0000u) + bb[1], 0.f);
        v0.z = fmaxf(__uint_as_float(u.y << 16)         + bb[2], 0.f);
        v0.w = fmaxf(__uint_as_float(u.y & 0xffff0000u) + bb[3], 0.f);
        v1.x = fmaxf(__uint_as_float(u.z << 16)         + bb[4], 0.f);
        v1.y = fmaxf(__uint_as_float(u.z & 0xffff0000u) + bb[5], 0.f);
        v1.z = fmaxf(__uint_as_float(u.w << 16)         + bb[6], 0.f);
        v1.w = fmaxf(__uint_as_float(u.w & 0xffff0000u) + bb[7], 0.f);
        al4[r * 33 + k8 * 2]     = v0;
        al4[r * 33 + k8 * 2 + 1] = v1;
    }
    __syncthreads();

    int f = t & 15, r0 = t >> 4;
    const float4* W4 = (const float4*)W2T;
    float acc0 = 0.f, acc1 = 0.f;
    #pragma unroll 8
    for (int k4 = 0; k4 < 32; ++k4) {
        float4 w  = W4[f * 33 + k4];
        float4 x0 = al4[r0 * 33 + k4];
        float4 x1 = al4[(r0 + 16) * 33 + k4];
        acc0 = fmaf(x0.x, w.x, acc0); acc0 = fmaf(x0.y, w.y, acc0);
        acc0 = fmaf(x0.z, w.z, acc0); acc0 = fmaf(x0.w, w.w, acc0);
        acc1 = fmaf(x1.x, w.x, acc1); acc1 = fmaf(x1.y, w.y, acc1);
        acc1 = fmaf(x1.z, w.z, acc1); acc1 = fmaf(x1.w, w.w, acc1);
    }
    if (row0 + r0 < N)      h2[(size_t)(row0 + r0) * 16 + f] = bf16rn(acc0);
    if (row0 + r0 + 16 < N) h2[(size_t)(row0 + r0 + 16) * 16 + f] = bf16rn(acc1);
}

// ---- L7: pull2 + log_softmax (8 lanes/row, 2 classes/lane) ----------------
__global__ __launch_bounds__(256) void k_pull2(
    const int* __restrict__ rs, const int* __restrict__ ssrc,
    const float* __restrict__ dinv, const uint32* __restrict__ h2,
    const float* __restrict__ b2, float* __restrict__ out, int N)
{
    int idx = blockIdx.x * 256 + threadIdx.x;
    int n = idx >> 3;
    if (n >= N) return;
    int c = idx & 7;
    int start = (n == 0) ? 0 : rs[n - 1];
    int end = rs[n];
    float dn = dinv[n];
    float acc0 = 0.f, acc1 = 0.f;
    for (int j = start; j < end; ++j) {
        int s = ssrc[j];
        float w = dn * dinv[s];
        uint32 u = h2[(size_t)s * 8 + c];
        acc0 = fmaf(w, __uint_as_float(u << 16), acc0);
        acc1 = fmaf(w, __uint_as_float(u & 0xffff0000u), acc1);
    }
    float v0 = acc0 + b2[2 * c];
    float v1 = acc1 + b2[2 * c + 1];
    float m = fmaxf(v0, v1);
    #pragma unroll
    for (int off = 1; off < 8; off <<= 1) m = fmaxf(m, __shfl_xor(m, off));
    float s = expf(v0 - m) + expf(v1 - m);
    #pragma unroll
    for (int off = 1; off < 8; off <<= 1) s += __shfl_xor(s, off);
    float ls = logf(s);
    float2 r = {v0 - m - ls, v1 - m - ls};
    ((float2*)out)[(size_t)n * 8 + c] = r;
}

extern "C" void kernel_launch(void* const* d_in, const int* in_sizes, int n_in,
                              void* d_out, int out_size, void* d_ws, size_t ws_size,
                              hipStream_t stream) {
    const float* x  = (const float*)d_in[0];
    const int*   ei = (const int*)d_in[1];
    const float* W1 = (const float*)d_in[2];
    const float* b1 = (const float*)d_in[3];
    const float* W2 = (const float*)d_in[4];
    const float* b2 = (const float*)d_in[5];
    float* outp = (float*)d_out;

    const int E = in_sizes[1] / 2;
    const int N = in_sizes[0] / 128;
    const int NB = (N + 255) >> 8;
    const int NH = (E + EH - 1) / EH;
    const int ntile = (N + 63) / 64;
    const int* src  = ei;
    const int* dstv = ei + E;

    const int Npad = (N + 255) & ~255;
    const int Epad = (E + 255) & ~255;
    int*   partials = (int*)d_ws;                   // [NH(<=128)][NBMAX]
    int*   bbase = partials + 128 * NBMAX;          // [NBMAX+1] (+pad)
    int*   bfill = bbase + NBMAX + 256;             // [NBMAX]
    int*   rs    = bfill + NBMAX;                   // [Npad]
    float* dinv  = (float*)(rs + Npad);             // [Npad]
    int2*  tmp   = (int2*)(dinv + Npad);            // [Epad]
    int*   ssrc  = (int*)(tmp + Epad);              // [Epad]
    u16*   h     = (u16*)(ssrc + Epad);             // N*128 bf16 (aliased h2)
    uint32* out1 = (uint32*)(h + (size_t)N * 128);  // N*64 packed bf16x2
    u16*   h2    = h;

    k_combo<<<ntile + NH, 256, 0, stream>>>(x, W1, dstv, partials, h, N, E, NB, ntile);
    k_scanB<<<1, 1024, 0, stream>>>(partials, bbase, bfill, NB, E, NH);
    k_partition<<<(E + CHUNK - 1) / CHUNK, 256, 0, stream>>>(src, dstv, bbase,
                                                             bfill, tmp, E, NB);
    k_bsort<<<NB, 256, 0, stream>>>(tmp, bbase, ssrc, rs, dinv, N);
    k_pull1<<<(N + 7) / 8, 256, 0, stream>>>(rs, ssrc, dinv,
                                             (const uint2*)h, (uint2*)out1, N);
    k_gemm2<<<(N + 31) / 32, 256, 0, stream>>>(out1, b1, W2, h2, N);
    k_pull2<<<(N * 8 + 255) / 256, 256, 0, stream>>>(rs, ssrc, dinv,
                                                     (const uint32*)h2, b2, outp, N);
}

// Round 13
// 196.082 us; speedup vs baseline: 1.8485x; 1.0244x over previous
//
#include <hip/hip_runtime.h>

// GCN 2-layer forward — 6-dispatch pipeline.
// Session rules learned: in-graph dispatch boundary ~1us (R9); grid.sync
// ~70us/sync (R8); intra-dispatch spin barriers serialize at low occupancy
// (R10); serial global-memory loops are latency poison (R11); pull1 is
// L2-fill/latency bound, not VMEM-inst bound (R12 flat).
// R13 (safe composite):
//   - pull1+gemm2 fused (k_pullg): 8 rows/block accumulated in registers ->
//     LDS (fp32, +b1, relu) -> in-block W2 dot -> h2. out1 round trip gone.
//   - tmp packed u32 (src 16b | dst&255 << 16)  [N <= 65535: N=50000]
//   - ssrc stored u16
// Pipeline: L1 combo(gemm1 MFMA || hist partials) -> L2 scanB -> L3 partition
//           -> L4 bsort -> L5 pullg -> L6 pull2+log_softmax

typedef unsigned int uint32;
typedef unsigned short u16;
typedef __attribute__((ext_vector_type(8))) short bf16x8;
typedef __attribute__((ext_vector_type(4))) float f32x4;

#define NBMAX 1024
#define CHUNK 4096
#define EH 8192   // edges per hist block

__device__ inline u16 bf16rn(float f) {
    unsigned u = __float_as_uint(f);
    return (u16)((u + 0x7fffu + ((u >> 16) & 1u)) >> 16);
}

__device__ inline void bffma(float2& a, float w, uint32 u) {
    a.x = fmaf(w, __uint_as_float(u << 16), a.x);
    a.y = fmaf(w, __uint_as_float(u & 0xffff0000u), a.y);
}

// ---- L1: gemm1 tiles || hist partial histograms ---------------------------
__global__ __launch_bounds__(256) void k_combo(
    const float* __restrict__ x, const float* __restrict__ W1,
    const int* __restrict__ dstv, int* __restrict__ partials,
    u16* __restrict__ h, int N, int E, int NB, int ntile)
{
    __shared__ __align__(16) unsigned char smem[128 * 136 * 2];  // 34816 B
    int t = threadIdx.x;

    if ((int)blockIdx.x >= ntile) {
        int* hl = (int*)smem;
        int hb = blockIdx.x - ntile;
        int e0 = hb * EH, e1 = min(e0 + EH, E);
        for (int i = t; i < NB; i += 256) hl[i] = 0;
        __syncthreads();
        for (int e = e0 + t; e < e1; e += 256)
            atomicAdd(&hl[dstv[e] >> 8], 1);
        __syncthreads();
        int* pr = partials + (size_t)hb * NBMAX;
        for (int i = t; i < NB; i += 256) pr[i] = hl[i];
        return;
    }

    // gemm1: h[N,128](bf16) = x @ W1, MFMA 16x16x32, W1 staged once
    u16* Wl = (u16*)smem;  // [n][k] pitch 136 (2-way bank aliasing: free)
    const float4* Wg4 = (const float4*)W1;
    for (int g = t; g < 128 * 32; g += 256) {
        int k = g >> 5, n4 = (g & 31) * 4;
        float4 v = Wg4[g];
        Wl[(n4 + 0) * 136 + k] = bf16rn(v.x);
        Wl[(n4 + 1) * 136 + k] = bf16rn(v.y);
        Wl[(n4 + 2) * 136 + k] = bf16rn(v.z);
        Wl[(n4 + 3) * 136 + k] = bf16rn(v.w);
    }
    __syncthreads();

    int wave = t >> 6, lane = t & 63;
    int quad = lane >> 4, ln = lane & 15;
    int rowbase = blockIdx.x * 64 + wave * 16;
    int rclamp = min(rowbase + ln, N - 1);

    f32x4 acc[8];
    #pragma unroll
    for (int ct = 0; ct < 8; ++ct) acc[ct] = (f32x4){0.f, 0.f, 0.f, 0.f};

    #pragma unroll
    for (int q = 0; q < 4; ++q) {
        const float4* xr = (const float4*)(x + (size_t)rclamp * 128 + q * 32 + quad * 8);
        float4 a0 = xr[0], a1 = xr[1];
        bf16x8 afr;
        afr[0] = (short)bf16rn(a0.x); afr[1] = (short)bf16rn(a0.y);
        afr[2] = (short)bf16rn(a0.z); afr[3] = (short)bf16rn(a0.w);
        afr[4] = (short)bf16rn(a1.x); afr[5] = (short)bf16rn(a1.y);
        afr[6] = (short)bf16rn(a1.z); afr[7] = (short)bf16rn(a1.w);
        #pragma unroll
        for (int ct = 0; ct < 8; ++ct) {
            bf16x8 bfr = *(const bf16x8*)&Wl[(ct * 16 + ln) * 136 + q * 32 + quad * 8];
            acc[ct] = __builtin_amdgcn_mfma_f32_16x16x32_bf16(afr, bfr, acc[ct], 0, 0, 0);
        }
    }
    #pragma unroll
    for (int i = 0; i < 4; ++i) {
        int r = rowbase + quad * 4 + i;
        if (r < N) {
            u16* hp = h + (size_t)r * 128 + ln;
            #pragma unroll
            for (int ct = 0; ct < 8; ++ct)
                hp[ct * 16] = bf16rn(acc[ct][i]);
        }
    }
}

// ---- L2: reduce partials, exclusive scan, zero bfill ----------------------
__global__ __launch_bounds__(1024) void k_scanB(
    const int* __restrict__ partials, int* __restrict__ bbase,
    int* __restrict__ bfill, int NB, int E, int NH)
{
    __shared__ int s[1024];
    int t = threadIdx.x;
    int v = 0;
    if (t < NB)
        for (int p = 0; p < NH; ++p) v += partials[(size_t)p * NBMAX + t];
    s[t] = v;
    __syncthreads();
    for (int off = 1; off < 1024; off <<= 1) {
        int u = (t >= off) ? s[t - off] : 0;
        __syncthreads();
        s[t] += u;
        __syncthreads();
    }
    if (t < NB) {
        bbase[t] = s[t] - v;
        bfill[t] = 0;
    }
    if (t == 0) bbase[NB] = E;
}

// ---- L3: partition edges into bucket regions (packed u32 records) ---------
__global__ __launch_bounds__(256) void k_partition(
    const int* __restrict__ src, const int* __restrict__ dstv,
    const int* __restrict__ bbase, int* __restrict__ bfill,
    uint32* __restrict__ tmp, int E, int NB)
{
    __shared__ int cntL[NBMAX];
    __shared__ int baseL[NBMAX];
    int t = threadIdx.x;
    int e0 = blockIdx.x * CHUNK;
    int e1 = min(e0 + CHUNK, E);
    for (int i = t; i < NB; i += 256) cntL[i] = 0;
    __syncthreads();
    for (int e = e0 + t; e < e1; e += 256)
        atomicAdd(&cntL[dstv[e] >> 8], 1);
    __syncthreads();
    for (int i = t; i < NB; i += 256) {
        int cc = cntL[i];
        baseL[i] = cc ? bbase[i] + atomicAdd(&bfill[i], cc) : 0;
        cntL[i] = 0;
    }
    __syncthreads();
    for (int e = e0 + t; e < e1; e += 256) {
        int sv = src[e], d = dstv[e];
        int b = d >> 8;
        int r = atomicAdd(&cntL[b], 1);
        tmp[baseL[b] + r] = (uint32)sv | ((uint32)(d & 255) << 16);
    }
}

// ---- L4: per-bucket exact sort; emit dinv / rs / ssrc(u16) ----------------
__global__ __launch_bounds__(256) void k_bsort(
    const uint32* __restrict__ tmp, const int* __restrict__ bbase,
    u16* __restrict__ ssrc, int* __restrict__ rs,
    float* __restrict__ dinv, int N)
{
    __shared__ int cnt[256];
    __shared__ int ofs[256];
    int t = threadIdx.x;
    int b = blockIdx.x;
    int base = bbase[b];
    int endb = bbase[b + 1];
    int node0 = b << 8;

    cnt[t] = 0;
    __syncthreads();
    for (int i = base + t; i < endb; i += 256)
        atomicAdd(&cnt[(tmp[i] >> 16) & 255], 1);
    __syncthreads();
    int v = cnt[t];
    __syncthreads();
    for (int off = 1; off < 256; off <<= 1) {
        int u = (t >= off) ? cnt[t - off] : 0;
        __syncthreads();
        cnt[t] += u;
        __syncthreads();
    }
    int node = node0 + t;
    if (node < N) {
        dinv[node] = rsqrtf(fmaxf((float)v, 1.0f));
        rs[node] = base + cnt[t];
    }
    ofs[t] = base + cnt[t] - v;
    __syncthreads();
    for (int i = base + t; i < endb; i += 256) {
        uint32 rec = tmp[i];
        int pos = atomicAdd(&ofs[(rec >> 16) & 255], 1);
        ssrc[pos] = (u16)(rec & 0xffffu);
    }
}

// ---- L5: pullg — fused pull1 + gemm2 --------------------------------------
// Per block: 8 rows (wave w -> rows 2w, 2w+1; half-wave per row, uint2
// payload). Row sums kept fp32, staged to LDS with +b1 and relu, then the
// in-block W2 dot produces h2[8 rows][16] (bf16).
__global__ __launch_bounds__(256) void k_pullg(
    const int* __restrict__ rs, const u16* __restrict__ ssrc,
    const float* __restrict__ dinv, const uint2* __restrict__ h,
    const float* __restrict__ b1, const float* __restrict__ W2,
    u16* __restrict__ h2, int N)
{
    __shared__ float W2T[16 * 132];   // [f][k] pitch 132
    __shared__ float rowbuf[8 * 132]; // [r][k] pitch 132 (float4 pitch 33)
    int t = threadIdx.x;

    // stage W2 transposed (needed only after the final barrier)
    for (int g = t; g < 2048; g += 256) {
        int k = g >> 4, f = g & 15;
        W2T[f * 132 + k] = W2[g];
    }

    int wave = t >> 6, lane = t & 63;
    int sub = lane >> 5;      // which row of the pair
    int rl = lane & 31;       // lane within half-wave (covers 32 uint2 = row)
    int rowbase = blockIdx.x * 8;
    int n = rowbase + wave * 2 + sub;
    bool valid = (n < N);
    int nc = valid ? n : 0;
    int start = valid ? ((nc == 0) ? 0 : rs[nc - 1]) : 0;
    int len   = valid ? (rs[nc] - start) : 0;
    float dn  = valid ? dinv[nc] : 0.f;
    int lenMax = max(len, __shfl_xor(len, 32));

    float2 aA[4], aB[4];
    #pragma unroll
    for (int k = 0; k < 4; ++k) {
        aA[k] = (float2){0.f, 0.f};
        aB[k] = (float2){0.f, 0.f};
    }

    for (int tt = 0; tt < lenMax; tt += 4) {
        int s[4];
        uint2 u[4];
        float w[4];
        #pragma unroll
        for (int k = 0; k < 4; ++k) {
            bool act = (tt + k) < len;            // uniform per half-wave
            int jj = act ? (start + tt + k) : 0;  // index 0 always valid
            s[k] = (int)ssrc[jj];
            w[k] = act ? 1.f : 0.f;
        }
        #pragma unroll
        for (int k = 0; k < 4; ++k)
            u[k] = h[(size_t)s[k] * 32 + rl];
        #pragma unroll
        for (int k = 0; k < 4; ++k)
            w[k] *= dn * dinv[s[k]];
        #pragma unroll
        for (int k = 0; k < 4; ++k) {
            bffma(aA[k], w[k], u[k].x);
            bffma(aB[k], w[k], u[k].y);
        }
    }

    // stage relu(row + b1) to LDS (fp32; cols 4rl..4rl+3 of row r)
    {
        int r = wave * 2 + sub;
        float4 bb = ((const float4*)b1)[rl];
        float4 v;
        v.x = fmaxf(((aA[0].x + aA[1].x) + (aA[2].x + aA[3].x)) + bb.x, 0.f);
        v.y = fmaxf(((aA[0].y + aA[1].y) + (aA[2].y + aA[3].y)) + bb.y, 0.f);
        v.z = fmaxf(((aB[0].x + aB[1].x) + (aB[2].x + aB[3].x)) + bb.z, 0.f);
        v.w = fmaxf(((aB[0].y + aB[1].y) + (aB[2].y + aB[3].y)) + bb.w, 0.f);
        ((float4*)rowbuf)[r * 33 + rl] = v;
    }
    __syncthreads();

    // in-block gemm2: h2[rowbase+r][f] = rowbuf[r] . W2T[f]
    if (t < 128) {
        int f = t & 15, r = t >> 4;
        const float4* W4 = (const float4*)W2T;   // pitch 33
        const float4* rb4 = (const float4*)rowbuf;
        float acc = 0.f;
        #pragma unroll 8
        for (int k4 = 0; k4 < 32; ++k4) {
            float4 w = W4[f * 33 + k4];
            float4 xv = rb4[r * 33 + k4];
            acc = fmaf(xv.x, w.x, acc);
            acc = fmaf(xv.y, w.y, acc);
            acc = fmaf(xv.z, w.z, acc);
            acc = fmaf(xv.w, w.w, acc);
        }
        int rn = rowbase + r;
        if (rn < N) h2[(size_t)rn * 16 + f] = bf16rn(acc);
    }
}

// ---- L6: pull2 + log_softmax (8 lanes/row, 2 classes/lane) ----------------
__global__ __launch_bounds__(256) void k_pull2(
    const int* __restrict__ rs, const u16* __restrict__ ssrc,
    const float* __restrict__ dinv, const uint32* __restrict__ h2,
    const float* __restrict__ b2, float* __restrict__ out, int N)
{
    int idx = blockIdx.x * 256 + threadIdx.x;
    int n = idx >> 3;
    if (n >= N) return;
    int c = idx & 7;
    int start = (n == 0) ? 0 : rs[n - 1];
    int end = rs[n];
    float dn = dinv[n];
    float acc0 = 0.f, acc1 = 0.f;
    for (int j = start; j < end; ++j) {
        int s = (int)ssrc[j];
        float w = dn * dinv[s];
        uint32 u = h2[(size_t)s * 8 + c];
        acc0 = fmaf(w, __uint_as_float(u << 16), acc0);
        acc1 = fmaf(w, __uint_as_float(u & 0xffff0000u), acc1);
    }
    float v0 = acc0 + b2[2 * c];
    float v1 = acc1 + b2[2 * c + 1];
    float m = fmaxf(v0, v1);
    #pragma unroll
    for (int off = 1; off < 8; off <<= 1) m = fmaxf(m, __shfl_xor(m, off));
    float s = expf(v0 - m) + expf(v1 - m);
    #pragma unroll
    for (int off = 1; off < 8; off <<= 1) s += __shfl_xor(s, off);
    float ls = logf(s);
    float2 r = {v0 - m - ls, v1 - m - ls};
    ((float2*)out)[(size_t)n * 8 + c] = r;
}

extern "C" void kernel_launch(void* const* d_in, const int* in_sizes, int n_in,
                              void* d_out, int out_size, void* d_ws, size_t ws_size,
                              hipStream_t stream) {
    const float* x  = (const float*)d_in[0];
    const int*   ei = (const int*)d_in[1];
    const float* W1 = (const float*)d_in[2];
    const float* b1 = (const float*)d_in[3];
    const float* W2 = (const float*)d_in[4];
    const float* b2 = (const float*)d_in[5];
    float* outp = (float*)d_out;

    const int E = in_sizes[1] / 2;
    const int N = in_sizes[0] / 128;   // N=50000 (fits u16 src packing)
    const int NB = (N + 255) >> 8;
    const int NH = (E + EH - 1) / EH;
    const int ntile = (N + 63) / 64;
    const int* src  = ei;
    const int* dstv = ei + E;

    const int Npad = (N + 255) & ~255;
    const int Epad = (E + 255) & ~255;
    int*   partials = (int*)d_ws;                   // [NH(<=128)][NBMAX]
    int*   bbase = partials + 128 * NBMAX;          // [NBMAX+1] (+pad)
    int*   bfill = bbase + NBMAX + 256;             // [NBMAX]
    int*   rs    = bfill + NBMAX;                   // [Npad]
    float* dinv  = (float*)(rs + Npad);             // [Npad]
    uint32* tmp  = (uint32*)(dinv + Npad);          // [Epad] packed src|dstlow
    u16*   ssrc  = (u16*)(tmp + Epad);              // [Epad] u16
    u16*   h     = (u16*)(ssrc + Epad);             // N*128 bf16 (aliased h2)
    u16*   h2    = h;

    k_combo<<<ntile + NH, 256, 0, stream>>>(x, W1, dstv, partials, h, N, E, NB, ntile);
    k_scanB<<<1, 1024, 0, stream>>>(partials, bbase, bfill, NB, E, NH);
    k_partition<<<(E + CHUNK - 1) / CHUNK, 256, 0, stream>>>(src, dstv, bbase,
                                                             bfill, tmp, E, NB);
    k_bsort<<<NB, 256, 0, stream>>>(tmp, bbase, ssrc, rs, dinv, N);
    k_pullg<<<(N + 7) / 8, 256, 0, stream>>>(rs, ssrc, dinv, (const uint2*)h,
                                             b1, W2, h2, N);
    k_pull2<<<(N * 8 + 255) / 256, 256, 0, stream>>>(rs, ssrc, dinv,
                                                     (const uint32*)h2, b2, outp, N);
}

// Round 14
// 190.389 us; speedup vs baseline: 1.9038x; 1.0299x over previous
//
#include <hip/hip_runtime.h>

// GCN 2-layer forward — 6-dispatch pipeline.
// Session rules: in-graph dispatch boundary ~1us (R9); grid.sync ~70us (R8);
// intra-dispatch spin barriers serialize (R10); serial global-memory loops
// are latency poison (R11); pull-gather is L2-fill bound, not VMEM-inst
// bound (R12); fp8 payloads excluded by error budget (absmax 0.031 vs
// threshold 0.058 after R13's fp32-path change).
// R14: pull2 4-deep unrolled (4 independent L2-hit loads in flight/lane).
// Pipeline: L1 combo(gemm1 MFMA || hist partials) -> L2 scanB -> L3 partition
//           -> L4 bsort -> L5 pullg(pull1+gemm2 fused) -> L6 pull2+lsm

typedef unsigned int uint32;
typedef unsigned short u16;
typedef __attribute__((ext_vector_type(8))) short bf16x8;
typedef __attribute__((ext_vector_type(4))) float f32x4;

#define NBMAX 1024
#define CHUNK 4096
#define EH 8192   // edges per hist block

__device__ inline u16 bf16rn(float f) {
    unsigned u = __float_as_uint(f);
    return (u16)((u + 0x7fffu + ((u >> 16) & 1u)) >> 16);
}

__device__ inline void bffma(float2& a, float w, uint32 u) {
    a.x = fmaf(w, __uint_as_float(u << 16), a.x);
    a.y = fmaf(w, __uint_as_float(u & 0xffff0000u), a.y);
}

// ---- L1: gemm1 tiles || hist partial histograms ---------------------------
__global__ __launch_bounds__(256) void k_combo(
    const float* __restrict__ x, const float* __restrict__ W1,
    const int* __restrict__ dstv, int* __restrict__ partials,
    u16* __restrict__ h, int N, int E, int NB, int ntile)
{
    __shared__ __align__(16) unsigned char smem[128 * 136 * 2];  // 34816 B
    int t = threadIdx.x;

    if ((int)blockIdx.x >= ntile) {
        int* hl = (int*)smem;
        int hb = blockIdx.x - ntile;
        int e0 = hb * EH, e1 = min(e0 + EH, E);
        for (int i = t; i < NB; i += 256) hl[i] = 0;
        __syncthreads();
        for (int e = e0 + t; e < e1; e += 256)
            atomicAdd(&hl[dstv[e] >> 8], 1);
        __syncthreads();
        int* pr = partials + (size_t)hb * NBMAX;
        for (int i = t; i < NB; i += 256) pr[i] = hl[i];
        return;
    }

    // gemm1: h[N,128](bf16) = x @ W1, MFMA 16x16x32, W1 staged once
    u16* Wl = (u16*)smem;  // [n][k] pitch 136 (2-way bank aliasing: free)
    const float4* Wg4 = (const float4*)W1;
    for (int g = t; g < 128 * 32; g += 256) {
        int k = g >> 5, n4 = (g & 31) * 4;
        float4 v = Wg4[g];
        Wl[(n4 + 0) * 136 + k] = bf16rn(v.x);
        Wl[(n4 + 1) * 136 + k] = bf16rn(v.y);
        Wl[(n4 + 2) * 136 + k] = bf16rn(v.z);
        Wl[(n4 + 3) * 136 + k] = bf16rn(v.w);
    }
    __syncthreads();

    int wave = t >> 6, lane = t & 63;
    int quad = lane >> 4, ln = lane & 15;
    int rowbase = blockIdx.x * 64 + wave * 16;
    int rclamp = min(rowbase + ln, N - 1);

    f32x4 acc[8];
    #pragma unroll
    for (int ct = 0; ct < 8; ++ct) acc[ct] = (f32x4){0.f, 0.f, 0.f, 0.f};

    #pragma unroll
    for (int q = 0; q < 4; ++q) {
        const float4* xr = (const float4*)(x + (size_t)rclamp * 128 + q * 32 + quad * 8);
        float4 a0 = xr[0], a1 = xr[1];
        bf16x8 afr;
        afr[0] = (short)bf16rn(a0.x); afr[1] = (short)bf16rn(a0.y);
        afr[2] = (short)bf16rn(a0.z); afr[3] = (short)bf16rn(a0.w);
        afr[4] = (short)bf16rn(a1.x); afr[5] = (short)bf16rn(a1.y);
        afr[6] = (short)bf16rn(a1.z); afr[7] = (short)bf16rn(a1.w);
        #pragma unroll
        for (int ct = 0; ct < 8; ++ct) {
            bf16x8 bfr = *(const bf16x8*)&Wl[(ct * 16 + ln) * 136 + q * 32 + quad * 8];
            acc[ct] = __builtin_amdgcn_mfma_f32_16x16x32_bf16(afr, bfr, acc[ct], 0, 0, 0);
        }
    }
    #pragma unroll
    for (int i = 0; i < 4; ++i) {
        int r = rowbase + quad * 4 + i;
        if (r < N) {
            u16* hp = h + (size_t)r * 128 + ln;
            #pragma unroll
            for (int ct = 0; ct < 8; ++ct)
                hp[ct * 16] = bf16rn(acc[ct][i]);
        }
    }
}

// ---- L2: reduce partials, exclusive scan, zero bfill ----------------------
__global__ __launch_bounds__(1024) void k_scanB(
    const int* __restrict__ partials, int* __restrict__ bbase,
    int* __restrict__ bfill, int NB, int E, int NH)
{
    __shared__ int s[1024];
    int t = threadIdx.x;
    int v = 0;
    if (t < NB)
        for (int p = 0; p < NH; ++p) v += partials[(size_t)p * NBMAX + t];
    s[t] = v;
    __syncthreads();
    for (int off = 1; off < 1024; off <<= 1) {
        int u = (t >= off) ? s[t - off] : 0;
        __syncthreads();
        s[t] += u;
        __syncthreads();
    }
    if (t < NB) {
        bbase[t] = s[t] - v;
        bfill[t] = 0;
    }
    if (t == 0) bbase[NB] = E;
}

// ---- L3: partition edges into bucket regions (packed u32 records) ---------
__global__ __launch_bounds__(256) void k_partition(
    const int* __restrict__ src, const int* __restrict__ dstv,
    const int* __restrict__ bbase, int* __restrict__ bfill,
    uint32* __restrict__ tmp, int E, int NB)
{
    __shared__ int cntL[NBMAX];
    __shared__ int baseL[NBMAX];
    int t = threadIdx.x;
    int e0 = blockIdx.x * CHUNK;
    int e1 = min(e0 + CHUNK, E);
    for (int i = t; i < NB; i += 256) cntL[i] = 0;
    __syncthreads();
    for (int e = e0 + t; e < e1; e += 256)
        atomicAdd(&cntL[dstv[e] >> 8], 1);
    __syncthreads();
    for (int i = t; i < NB; i += 256) {
        int cc = cntL[i];
        baseL[i] = cc ? bbase[i] + atomicAdd(&bfill[i], cc) : 0;
        cntL[i] = 0;
    }
    __syncthreads();
    for (int e = e0 + t; e < e1; e += 256) {
        int sv = src[e], d = dstv[e];
        int b = d >> 8;
        int r = atomicAdd(&cntL[b], 1);
        tmp[baseL[b] + r] = (uint32)sv | ((uint32)(d & 255) << 16);
    }
}

// ---- L4: per-bucket exact sort; emit dinv / rs / ssrc(u16) ----------------
__global__ __launch_bounds__(256) void k_bsort(
    const uint32* __restrict__ tmp, const int* __restrict__ bbase,
    u16* __restrict__ ssrc, int* __restrict__ rs,
    float* __restrict__ dinv, int N)
{
    __shared__ int cnt[256];
    __shared__ int ofs[256];
    int t = threadIdx.x;
    int b = blockIdx.x;
    int base = bbase[b];
    int endb = bbase[b + 1];
    int node0 = b << 8;

    cnt[t] = 0;
    __syncthreads();
    for (int i = base + t; i < endb; i += 256)
        atomicAdd(&cnt[(tmp[i] >> 16) & 255], 1);
    __syncthreads();
    int v = cnt[t];
    __syncthreads();
    for (int off = 1; off < 256; off <<= 1) {
        int u = (t >= off) ? cnt[t - off] : 0;
        __syncthreads();
        cnt[t] += u;
        __syncthreads();
    }
    int node = node0 + t;
    if (node < N) {
        dinv[node] = rsqrtf(fmaxf((float)v, 1.0f));
        rs[node] = base + cnt[t];
    }
    ofs[t] = base + cnt[t] - v;
    __syncthreads();
    for (int i = base + t; i < endb; i += 256) {
        uint32 rec = tmp[i];
        int pos = atomicAdd(&ofs[(rec >> 16) & 255], 1);
        ssrc[pos] = (u16)(rec & 0xffffu);
    }
}

// ---- L5: pullg — fused pull1 + gemm2 --------------------------------------
__global__ __launch_bounds__(256) void k_pullg(
    const int* __restrict__ rs, const u16* __restrict__ ssrc,
    const float* __restrict__ dinv, const uint2* __restrict__ h,
    const float* __restrict__ b1, const float* __restrict__ W2,
    u16* __restrict__ h2, int N)
{
    __shared__ float W2T[16 * 132];   // [f][k] pitch 132
    __shared__ float rowbuf[8 * 132]; // [r][k] pitch 132 (float4 pitch 33)
    int t = threadIdx.x;

    for (int g = t; g < 2048; g += 256) {
        int k = g >> 4, f = g & 15;
        W2T[f * 132 + k] = W2[g];
    }

    int wave = t >> 6, lane = t & 63;
    int sub = lane >> 5;
    int rl = lane & 31;
    int rowbase = blockIdx.x * 8;
    int n = rowbase + wave * 2 + sub;
    bool valid = (n < N);
    int nc = valid ? n : 0;
    int start = valid ? ((nc == 0) ? 0 : rs[nc - 1]) : 0;
    int len   = valid ? (rs[nc] - start) : 0;
    float dn  = valid ? dinv[nc] : 0.f;
    int lenMax = max(len, __shfl_xor(len, 32));

    float2 aA[4], aB[4];
    #pragma unroll
    for (int k = 0; k < 4; ++k) {
        aA[k] = (float2){0.f, 0.f};
        aB[k] = (float2){0.f, 0.f};
    }

    for (int tt = 0; tt < lenMax; tt += 4) {
        int s[4];
        uint2 u[4];
        float w[4];
        #pragma unroll
        for (int k = 0; k < 4; ++k) {
            bool act = (tt + k) < len;
            int jj = act ? (start + tt + k) : 0;
            s[k] = (int)ssrc[jj];
            w[k] = act ? 1.f : 0.f;
        }
        #pragma unroll
        for (int k = 0; k < 4; ++k)
            u[k] = h[(size_t)s[k] * 32 + rl];
        #pragma unroll
        for (int k = 0; k < 4; ++k)
            w[k] *= dn * dinv[s[k]];
        #pragma unroll
        for (int k = 0; k < 4; ++k) {
            bffma(aA[k], w[k], u[k].x);
            bffma(aB[k], w[k], u[k].y);
        }
    }

    {
        int r = wave * 2 + sub;
        float4 bb = ((const float4*)b1)[rl];
        float4 v;
        v.x = fmaxf(((aA[0].x + aA[1].x) + (aA[2].x + aA[3].x)) + bb.x, 0.f);
        v.y = fmaxf(((aA[0].y + aA[1].y) + (aA[2].y + aA[3].y)) + bb.y, 0.f);
        v.z = fmaxf(((aB[0].x + aB[1].x) + (aB[2].x + aB[3].x)) + bb.z, 0.f);
        v.w = fmaxf(((aB[0].y + aB[1].y) + (aB[2].y + aB[3].y)) + bb.w, 0.f);
        ((float4*)rowbuf)[r * 33 + rl] = v;
    }
    __syncthreads();

    if (t < 128) {
        int f = t & 15, r = t >> 4;
        const float4* W4 = (const float4*)W2T;
        const float4* rb4 = (const float4*)rowbuf;
        float acc = 0.f;
        #pragma unroll 8
        for (int k4 = 0; k4 < 32; ++k4) {
            float4 w = W4[f * 33 + k4];
            float4 xv = rb4[r * 33 + k4];
            acc = fmaf(xv.x, w.x, acc);
            acc = fmaf(xv.y, w.y, acc);
            acc = fmaf(xv.z, w.z, acc);
            acc = fmaf(xv.w, w.w, acc);
        }
        int rn = rowbase + r;
        if (rn < N) h2[(size_t)rn * 16 + f] = bf16rn(acc);
    }
}

// ---- L6: pull2 + log_softmax, 4-deep unroll -------------------------------
__global__ __launch_bounds__(256) void k_pull2(
    const int* __restrict__ rs, const u16* __restrict__ ssrc,
    const float* __restrict__ dinv, const uint32* __restrict__ h2,
    const float* __restrict__ b2, float* __restrict__ out, int N)
{
    int idx = blockIdx.x * 256 + threadIdx.x;
    int n = idx >> 3;
    if (n >= N) return;
    int c = idx & 7;
    int start = (n == 0) ? 0 : rs[n - 1];
    int len = rs[n] - start;
    float dn = dinv[n];

    float2 a[4];
    #pragma unroll
    for (int k = 0; k < 4; ++k) a[k] = (float2){0.f, 0.f};

    for (int tt = 0; tt < len; tt += 4) {
        int s[4];
        uint32 u[4];
        float w[4];
        #pragma unroll
        for (int k = 0; k < 4; ++k) {
            bool act = (tt + k) < len;
            int jj = act ? (start + tt + k) : 0;   // index 0 always valid
            s[k] = (int)ssrc[jj];
            w[k] = act ? 1.f : 0.f;
        }
        #pragma unroll
        for (int k = 0; k < 4; ++k)
            u[k] = h2[(size_t)s[k] * 8 + c];
        #pragma unroll
        for (int k = 0; k < 4; ++k)
            w[k] *= dn * dinv[s[k]];
        #pragma unroll
        for (int k = 0; k < 4; ++k)
            bffma(a[k], w[k], u[k]);
    }

    float acc0 = (a[0].x + a[1].x) + (a[2].x + a[3].x);
    float acc1 = (a[0].y + a[1].y) + (a[2].y + a[3].y);
    float v0 = acc0 + b2[2 * c];
    float v1 = acc1 + b2[2 * c + 1];
    float m = fmaxf(v0, v1);
    #pragma unroll
    for (int off = 1; off < 8; off <<= 1) m = fmaxf(m, __shfl_xor(m, off));
    float s = expf(v0 - m) + expf(v1 - m);
    #pragma unroll
    for (int off = 1; off < 8; off <<= 1) s += __shfl_xor(s, off);
    float ls = logf(s);
    float2 r = {v0 - m - ls, v1 - m - ls};
    ((float2*)out)[(size_t)n * 8 + c] = r;
}

extern "C" void kernel_launch(void* const* d_in, const int* in_sizes, int n_in,
                              void* d_out, int out_size, void* d_ws, size_t ws_size,
                              hipStream_t stream) {
    const float* x  = (const float*)d_in[0];
    const int*   ei = (const int*)d_in[1];
    const float* W1 = (const float*)d_in[2];
    const float* b1 = (const float*)d_in[3];
    const float* W2 = (const float*)d_in[4];
    const float* b2 = (const float*)d_in[5];
    float* outp = (float*)d_out;

    const int E = in_sizes[1] / 2;
    const int N = in_sizes[0] / 128;   // N=50000 (fits u16 src packing)
    const int NB = (N + 255) >> 8;
    const int NH = (E + EH - 1) / EH;
    const int ntile = (N + 63) / 64;
    const int* src  = ei;
    const int* dstv = ei + E;

    const int Npad = (N + 255) & ~255;
    const int Epad = (E + 255) & ~255;
    int*   partials = (int*)d_ws;                   // [NH(<=128)][NBMAX]
    int*   bbase = partials + 128 * NBMAX;          // [NBMAX+1] (+pad)
    int*   bfill = bbase + NBMAX + 256;             // [NBMAX]
    int*   rs    = bfill + NBMAX;                   // [Npad]
    float* dinv  = (float*)(rs + Npad);             // [Npad]
    uint32* tmp  = (uint32*)(dinv + Npad);          // [Epad] packed src|dstlow
    u16*   ssrc  = (u16*)(tmp + Epad);              // [Epad] u16
    u16*   h     = (u16*)(ssrc + Epad);             // N*128 bf16 (aliased h2)
    u16*   h2    = h;

    k_combo<<<ntile + NH, 256, 0, stream>>>(x, W1, dstv, partials, h, N, E, NB, ntile);
    k_scanB<<<1, 1024, 0, stream>>>(partials, bbase, bfill, NB, E, NH);
    k_partition<<<(E + CHUNK - 1) / CHUNK, 256, 0, stream>>>(src, dstv, bbase,
                                                             bfill, tmp, E, NB);
    k_bsort<<<NB, 256, 0, stream>>>(tmp, bbase, ssrc, rs, dinv, N);
    k_pullg<<<(N + 7) / 8, 256, 0, stream>>>(rs, ssrc, dinv, (const uint2*)h,
                                             b1, W2, h2, N);
    k_pull2<<<(N * 8 + 255) / 256, 256, 0, stream>>>(rs, ssrc, dinv,
                                                     (const uint32*)h2, b2, outp, N);
}